// Round 15
// baseline (209.401 us; speedup 1.0000x reference)
//
#include <hip/hip_runtime.h>
#include <hip/hip_bf16.h>
#include <hip/hip_fp16.h>

// adj = W@W^T (N=16384, D=128), per-row top-32, cols sorted ascending.
// out (f32, concat): [NK) row ids | [NK) sorted col idx | [NK) values.
//
//  r14 post-mortem: fused is ~2x from an L1-BW floor set by B-fragment
//  BYTES (8 KB/wave/stage bf16). This round halves bytes AND MFMA count:
//  i8 MFMA 32x32x32 (2x K, 2x rate). Self-quantization identity:
//  quantizing w/||w|| by 126/max|a| == quantizing w by 126/max|w| -> ONE
//  2 MB i8 table serves both A and B; score' = i32acc*invA[r]*invB[c].
//  Score noise sigma ~0.020 (vs bf16 0.0027) -> DELTA 0.14 (5.9 sigma over
//  1.9M candidates), WCAP 64; sandwich machinery unchanged (valid r5-r14).
//
//  K1 pack: LDS transpose; per-row norm + absmax; emit FQ (i8, fragment
//           layout addr(c,k) = (c>>5)*4096 + (k>>4)*512 + (c&31)*16 + (k&15)),
//           invA = amax/(126*norm), invB = amax/126, norm.
//  K2 fused: r14 structure (RPB=32, 512thr, grid 512, stagger, 2 blk/CU);
//           afrag int4v[4] (16 regs), 4 i8-MFMAs/stage, scatter with
//           v = float(acc)*invA16[r]*invb. Tail: histogram cut, sure-in,
//           f64 window rescore (one/lane), col-sort, write.

#define N_ROWS 16384
#define DIM    128
#define TOPK   32
#define NK     (N_ROWS * TOPK)
#define ZTAU   2.45f
#define DELTA  0.14f
#define CAPL   192            // slots/row (mean ~118)
#define WCAP   64             // window mean ~27 at DELTA=0.14
#define RPB    32
#define NWAVE  8
#define CPS    256            // cols per stage = 8 waves x 32
#define NSTG   (N_ROWS / CPS) // 64
#define W1BIN  0.15625f
#define W2BIN  0.00244140625f

using int4v    = __attribute__((ext_vector_type(4)))  int;
using intx16   = __attribute__((ext_vector_type(16))) int;

// ---------------- K1: LDS-transposed i8 pack + norms/scales ----------------
#define PK_ROWS 64
__global__ __launch_bounds__(256)
void pack_kernel(const float* __restrict__ W, signed char* __restrict__ FQ,
                 float* __restrict__ invA, float* __restrict__ invB,
                 float* __restrict__ norm) {
    __shared__ float lds[PK_ROWS * 132];
    __shared__ float nrmS[PK_ROWS], amxS[PK_ROWS];
    const int t  = threadIdx.x;
    const int rb = blockIdx.x * PK_ROWS;

    // phase 1: coalesced read -> LDS; per-row norm + absmax (32-lane shfl)
    const float4* src = (const float4*)(W + (size_t)rb * DIM);
    #pragma unroll
    for (int i = 0; i < 8; ++i) {
        const int f = t + 256 * i;
        const float4 v = src[f];
        const int r = f >> 5, j = f & 31;
        *(float4*)&lds[r * 132 + j * 4] = v;
        float ss = v.x * v.x + v.y * v.y + v.z * v.z + v.w * v.w;
        float am = fmaxf(fmaxf(fabsf(v.x), fabsf(v.y)), fmaxf(fabsf(v.z), fabsf(v.w)));
        #pragma unroll
        for (int off = 1; off < 32; off <<= 1) {
            ss += __shfl_xor(ss, off, 64);
            am = fmaxf(am, __shfl_xor(am, off, 64));
        }
        if (j == 0) { nrmS[r] = sqrtf(ss); amxS[r] = am; }
    }
    __syncthreads();

    // phase 2: read LDS in fragment order, quantize, coalesced dword stores
    unsigned* fq = (unsigned*)(FQ + (size_t)blockIdx.x * 8192);
    #pragma unroll
    for (int i = 0; i < 8; ++i) {
        const int d   = t + 256 * i;                // output dword, coalesced
        const int fb  = d >> 10, rem = d & 1023;
        const int q   = rem >> 7, c31 = (rem >> 2) & 31, sub = rem & 3;
        const int row = fb * 32 + c31;
        const float4 v = *(const float4*)&lds[row * 132 + q * 16 + sub * 4];
        const float sc = 126.0f / amxS[row];
        const int q0 = (int)rintf(v.x * sc), q1 = (int)rintf(v.y * sc);
        const int q2 = (int)rintf(v.z * sc), q3 = (int)rintf(v.w * sc);
        fq[d] = (unsigned)(q0 & 255) | ((unsigned)(q1 & 255) << 8)
              | ((unsigned)(q2 & 255) << 16) | ((unsigned)(q3 & 255) << 24);
    }
    if (t < PK_ROWS) {
        norm[rb + t] = nrmS[t];
        invA[rb + t] = amxS[t] / (126.0f * nrmS[t]);
        invB[rb + t] = amxS[t] / 126.0f;
    }
}

// ---------------- K2: fused i8 score + select + write ----------------
__global__ __launch_bounds__(512, 4)
void fused_kernel(const signed char* __restrict__ FQ,
                  const float* __restrict__ invA, const float* __restrict__ invB,
                  const float* __restrict__ W, const float* __restrict__ norm,
                  float* __restrict__ out) {
    __shared__ unsigned int scnt[RPB];
    __shared__ unsigned int candL[RPB * CAPL];         // 24 KiB
    __shared__ int          wcolS[NWAVE][WCAP];
    __shared__ double       dvalS[NWAVE][WCAP];        // hist overlays here
    __shared__ int          fcolS[NWAVE][TOPK];
    __shared__ float        fvalS[NWAVE][TOPK];
    __shared__ unsigned int wcntS[NWAVE], mcntS[NWAVE], fcntS[NWAVE];

    const int tid = threadIdx.x, lane = tid & 63, wid = tid >> 6;
    const int half = lane >> 5, l31 = lane & 31;
    const int rowbase = blockIdx.x * RPB;

    if (tid < RPB) scnt[tid] = 0u;
    __syncthreads();

    // A-frags: 4 x int4v (16 regs), coalesced 1 KiB loads from FQ
    int4v afrag[4];
    {
        const char* ab = (const char*)FQ + (size_t)(rowbase >> 5) * 4096
                       + half * 512 + l31 * 16;
        #pragma unroll
        for (int kt = 0; kt < 4; ++kt) afrag[kt] = *(const int4v*)(ab + kt * 1024);
    }
    const int rbh = 4 * half;                          // C/D row=(r&3)+8*(r>>2)+4*half
    float invA16[16];
    #pragma unroll
    for (int r = 0; r < 16; ++r)
        invA16[r] = invA[rowbase + rbh + (r & 3) + 8 * (r >> 2)];

    const char* bstream = (const char*)FQ + (size_t)wid * 4096 + half * 512 + l31 * 16;
    // stagger: co-resident pair (b, b+256) in phase (L1 share); CUs decorrelated
    const int s0 = (37 * (blockIdx.x & 255)) & (NSTG - 1);

    for (int i = 0; i < NSTG; ++i) {
        const int s = (s0 + i) & (NSTG - 1);
        const char* bp = bstream + (size_t)s * 32768;   // 256 cols x 128 B
        const float invb = invB[s * CPS + wid * 32 + l31];
        int4v bfr[4];
        #pragma unroll
        for (int kt = 0; kt < 4; ++kt) bfr[kt] = *(const int4v*)(bp + kt * 1024);
        intx16 acc = (intx16)0;
        #pragma unroll
        for (int kt = 0; kt < 4; ++kt)
            acc = __builtin_amdgcn_mfma_i32_32x32x32_i8(afrag[kt], bfr[kt], acc, 0, 0, 0);

        const unsigned pcol = (unsigned)(s * CPS + wid * 32 + l31) << 16;
        #pragma unroll
        for (int r = 0; r < 16; ++r) {
            const float v = (float)acc[r] * invA16[r] * invb;
            if (v > ZTAU) {
                const int rloc = rbh + (r & 3) + 8 * (r >> 2);
                unsigned slot = atomicAdd(&scnt[rloc], 1u);
                if (slot < CAPL)
                    candL[rloc * CAPL + slot] = pcol | __half_as_ushort(__float2half(v));
            }
        }
    }
    __syncthreads();

    // -------- tail: wave wid owns rows wid*4 .. wid*4+3 (validated r5-r14) --------
    unsigned int* histW = (unsigned int*)&dvalS[wid][0];   // overlay (dead here)
    for (int rr = 0; rr < 4; ++rr) {
        const int rloc = wid * 4 + rr;
        const int rowg = rowbase + rloc;
        int n = (int)scnt[rloc]; if (n > CAPL) n = CAPL;
        const unsigned int* cl = &candL[rloc * CAPL];

        if (lane == 0) { wcntS[wid] = 0u; mcntS[wid] = 0u; fcntS[wid] = 0u; }
        // level-1 histogram over [ZTAU, ZTAU+10)
        histW[lane] = 0u;
        for (int i = lane; i < n; i += 64) {
            const float v = __half2float(__ushort_as_half((unsigned short)(cl[i] & 0xFFFFu)));
            int b = (int)((v - ZTAU) * (1.0f / W1BIN));
            b = b < 0 ? 0 : (b > 63 ? 63 : b);
            atomicAdd(&histW[b], 1u);
        }
        unsigned sfx = histW[lane];
        #pragma unroll
        for (int off = 1; off < 64; off <<= 1) {
            unsigned u = __shfl_down(sfx, off, 64);
            if (lane + off < 64) sfx += u;
        }
        unsigned long long mk = __ballot(sfx >= (unsigned)TOPK);
        const int b1 = mk ? (63 - __clzll(mk)) : 0;
        unsigned Gup = __shfl(sfx, (b1 + 1) & 63, 64);
        if (b1 == 63) Gup = 0u;
        const float lo1 = ZTAU + (float)b1 * W1BIN;

        // level-2 histogram within [lo1, lo1+W1BIN)
        histW[lane] = 0u;
        for (int i = lane; i < n; i += 64) {
            const float v = __half2float(__ushort_as_half((unsigned short)(cl[i] & 0xFFFFu)));
            if (v >= lo1 && v < lo1 + W1BIN) {
                int b = (int)((v - lo1) * (1.0f / W2BIN));
                b = b < 0 ? 0 : (b > 63 ? 63 : b);
                atomicAdd(&histW[b], 1u);
            }
        }
        unsigned sfx2 = histW[lane];
        #pragma unroll
        for (int off = 1; off < 64; off <<= 1) {
            unsigned u = __shfl_down(sfx2, off, 64);
            if (lane + off < 64) sfx2 += u;
        }
        sfx2 += Gup;
        mk = __ballot(sfx2 >= (unsigned)TOPK);
        const int b2 = mk ? (63 - __clzll(mk)) : 0;
        const float vlo = lo1 + (float)b2 * W2BIN;       // s32 in [vlo, vhi)
        const float vhi = vlo + W2BIN;

        // classify: sure-in / window
        for (int i = lane; i < n; i += 64) {
            const unsigned e = cl[i];
            const float v = __half2float(__ushort_as_half((unsigned short)(e & 0xFFFFu)));
            if (v > vhi + DELTA) {
                atomicAdd(&mcntS[wid], 1u);
            } else if (v >= vlo - DELTA) {
                unsigned u = atomicAdd(&wcntS[wid], 1u);
                if (u < WCAP) wcolS[wid][u] = (int)(e >> 16);
            }
        }
        const int m = (int)mcntS[wid];
        int wn = (int)wcntS[wid]; if (wn > WCAP) wn = WCAP;
        int need = TOPK - m; if (need < 0) need = 0;

        // exact f64 rescore of window, one member per lane (parallel gather)
        if (lane < wn) {
            const int col = wcolS[wid][lane] & (N_ROWS - 1);
            const float4* wa = (const float4*)(W + (size_t)rowg * DIM);
            const float4* wb = (const float4*)(W + (size_t)col * DIM);
            double d0 = 0, d1 = 0, d2 = 0, d3 = 0;
            #pragma unroll
            for (int k = 0; k < DIM / 4; ++k) {
                const float4 x = wa[k]; const float4 y = wb[k];
                d0 += (double)x.x * y.x; d1 += (double)x.y * y.y;
                d2 += (double)x.z * y.z; d3 += (double)x.w * y.w;
            }
            dvalS[wid][lane] = (d0 + d1) + (d2 + d3);
        }
        // top-`need` of window by (exact desc, col asc)
        if (lane < wn) {
            const double dv = dvalS[wid][lane]; const int c = wcolS[wid][lane];
            int r = 0;
            for (int u = 0; u < wn; ++u) {
                const double du = dvalS[wid][u];
                r += (du > dv || (du == dv && wcolS[wid][u] < c)) ? 1 : 0;
            }
            if (r < need) {
                unsigned slot = atomicAdd(&fcntS[wid], 1u);
                if (slot < TOPK) { fcolS[wid][slot] = c; fvalS[wid][slot] = (float)dv; }
            }
        }
        // sure-ins: value = stored fp16 score' * norm (validated r6-r14)
        const float nm = norm[rowg];
        for (int i = lane; i < n; i += 64) {
            const unsigned e = cl[i];
            const float v = __half2float(__ushort_as_half((unsigned short)(e & 0xFFFFu)));
            if (v > vhi + DELTA) {
                unsigned slot = atomicAdd(&fcntS[wid], 1u);
                if (slot < TOPK) { fcolS[wid][slot] = (int)(e >> 16); fvalS[wid][slot] = v * nm; }
            }
        }
        int fn = (int)fcntS[wid]; if (fn > TOPK) fn = TOPK;
        // sort <=32 finalists by col, write all 3 segments
        if (lane < fn) {
            const int c = fcolS[wid][lane];
            int pos = 0;
            for (int j = 0; j < fn; ++j) pos += (fcolS[wid][j] < c) ? 1 : 0;
            const size_t base = (size_t)rowg * TOPK + pos;
            out[base]                  = (float)rowg;
            out[NK + base]             = (float)c;
            out[2 * (size_t)NK + base] = fvalS[wid][lane];
        }
    }
}

extern "C" void kernel_launch(void* const* d_in, const int* in_sizes, int n_in,
                              void* d_out, int out_size, void* d_ws, size_t ws_size,
                              hipStream_t stream) {
    (void)in_sizes; (void)n_in; (void)out_size; (void)ws_size;
    const float* W   = (const float*)d_in[1];        // d_in[0] = x (unused)
    float*       out = (float*)d_out;

    char* ws = (char*)d_ws;                          // ~2.2 MiB used
    signed char* FQ   = (signed char*)ws;                            // 2 MiB i8 frag layout
    float*       norm = (float*)(ws + (size_t)2097152);              // 64 KiB
    float*       invA = (float*)(ws + (size_t)2162688);              // 64 KiB
    float*       invB = (float*)(ws + (size_t)2228224);              // 64 KiB

    pack_kernel<<<N_ROWS / PK_ROWS, 256, 0, stream>>>(W, FQ, invA, invB, norm);
    fused_kernel<<<N_ROWS / RPB, 512, 0, stream>>>(FQ, invA, invB, W, norm, out);
}